// Round 8
// baseline (280.740 us; speedup 1.0000x reference)
//
#include <hip/hip_runtime.h>
#include <math.h>

#define D 1024
#define NH 16
#define DK 64
#define S_LEN 2048
// 0.125 (1/sqrt(Dk)) * log2(e): softmax computed in base-2 domain, no max-subtraction
#define QSCALE 0.18033688011112f

using short8 = __attribute__((ext_vector_type(8))) short;   // 8 x bf16 (4 VGPR)
using f32x4  = __attribute__((ext_vector_type(4))) float;   // MFMA accumulator

#define MFMA16(a, b, c) __builtin_amdgcn_mfma_f32_16x16x32_bf16((a), (b), (c), 0, 0, 0)
#define EXP2F(x) __builtin_amdgcn_exp2f(x)

__device__ inline unsigned short f2bf(float f) {
    union { float f; unsigned u; } v; v.f = f;
    unsigned r = v.u + 0x7fffu + ((v.u >> 16) & 1u);
    return (unsigned short)(r >> 16);
}

// async global->LDS, 16B/lane; LDS dest = ldsbase + lane*16 (wave-uniform base)
__device__ inline void gload16(const unsigned short* g, unsigned short* l) {
    __builtin_amdgcn_global_load_lds(
        (const __attribute__((address_space(1))) void*)g,
        (__attribute__((address_space(3))) void*)l, 16, 0, 0);
}

// ---------------- fused fp32 -> bf16 for all 7 tensors in one dispatch --------
struct CvtP {
    const float* s[7];
    unsigned short* d[7];
};
__global__ __launch_bounds__(256) void cvt_all(CvtP p, int inpBlocks, int wBlocks) {
    int bx = blockIdx.x;
    int seg, boff;
    if (bx < 3 * inpBlocks) { seg = bx / inpBlocks; boff = bx - seg * inpBlocks; }
    else { int t = bx - 3 * inpBlocks; seg = 3 + t / wBlocks; boff = t - (seg - 3) * wBlocks; }
    int i = (boff * 256 + threadIdx.x) * 4;
    float4 f = *(const float4*)(p.s[seg] + i);
    ushort4 u;
    u.x = f2bf(f.x); u.y = f2bf(f.y); u.z = f2bf(f.z); u.w = f2bf(f.w);
    *(ushort4*)(p.d[seg] + i) = u;
}

// Fragment-swizzled layouts (per (b,h), element stride in shorts):
//  Q_sw/K_sw: [s/16 block][panel d/32][lane = (s&15) + 16*((d&31)/8)][i = d&7]
//             offset = blk16*1024 + panel*512 + lane*8 + i     (256 KB per bh)
//  V_sw:      kv'-PERMUTED within each 64-tile: kv' = 4*(kv&15) + (kv>>4)
//             (matches P stash order col' = 4r + j; softmax/PV are invariant
//              to a kv permutation applied consistently to P and V)
//             [kv/64 tile][nb = d/16][p = kv'/32][lane = (d&15) + 16*((kv'&31)/8)][i = kv'&7]
// A wave's MFMA fragment load is then one coalesced b128 at base + lane*16B.

// ---------------- fused QKV projection GEMM, 128x128 tile, BK=64 --------------
// out = X @ W^T + b. BM=128 BN=128 BK=64 (one barrier pair per 64-k chunk,
// 32 MFMA per barrier). 256 thr, 4 waves in 2x2, each 64x64.
__global__ __launch_bounds__(256) void gemm_qkv(
    const unsigned short* __restrict__ qb, const unsigned short* __restrict__ kb,
    const unsigned short* __restrict__ vb,
    const unsigned short* __restrict__ Wqb, const unsigned short* __restrict__ Wkb,
    const unsigned short* __restrict__ Wvb,
    const float* __restrict__ bq, const float* __restrict__ bk, const float* __restrict__ bv,
    unsigned short* __restrict__ Qs, unsigned short* __restrict__ Ks,
    unsigned short* __restrict__ Vs)
{
    __shared__ unsigned short sA[128 * 64];   // 16 KB
    __shared__ unsigned short sB[128 * 64];   // 16 KB

    const int z = blockIdx.z;
    const unsigned short* X = (z == 0) ? qb : (z == 1) ? kb : vb;
    const unsigned short* W = (z == 0) ? Wqb : (z == 1) ? Wkb : Wvb;
    const float* bias = (z == 0) ? bq : (z == 1) ? bk : bv;

    const int tid = threadIdx.x, lane = tid & 63, w = tid >> 6;
    const int wy = w & 1, wx = w >> 1, r = lane & 15, q = lane >> 4;
    const int m0 = blockIdx.x * 128, n0 = blockIdx.y * 128;
    const int lrow = tid >> 3, lkc = (tid & 7) * 8;   // 32 rows x 64 cols per call line

    const unsigned short* Xg = X + (size_t)(m0 + lrow) * D + lkc;
    const unsigned short* Wg = W + (size_t)(n0 + lrow) * D + lkc;

    f32x4 acc[4][4];
    #pragma unroll
    for (int mi = 0; mi < 4; ++mi)
        #pragma unroll
        for (int ni = 0; ni < 4; ++ni) acc[mi][ni] = (f32x4){0.f, 0.f, 0.f, 0.f};

    for (int k0 = 0; k0 < D; k0 += 64) {
        __syncthreads();
        gload16(Xg + k0,          sA + w * 512);
        gload16(Xg + 32 * D + k0, sA + 2048 + w * 512);
        gload16(Xg + 64 * D + k0, sA + 4096 + w * 512);
        gload16(Xg + 96 * D + k0, sA + 6144 + w * 512);
        gload16(Wg + k0,          sB + w * 512);
        gload16(Wg + 32 * D + k0, sB + 2048 + w * 512);
        gload16(Wg + 64 * D + k0, sB + 4096 + w * 512);
        gload16(Wg + 96 * D + k0, sB + 6144 + w * 512);
        __syncthreads();
        #pragma unroll
        for (int c = 0; c < 2; ++c) {
            short8 af[4], bfr[4];
            #pragma unroll
            for (int mi = 0; mi < 4; ++mi)
                af[mi] = *(const short8*)(sA + (wy * 64 + mi * 16 + r) * 64 + c * 32 + q * 8);
            #pragma unroll
            for (int ni = 0; ni < 4; ++ni)
                bfr[ni] = *(const short8*)(sB + (wx * 64 + ni * 16 + r) * 64 + c * 32 + q * 8);
            #pragma unroll
            for (int mi = 0; mi < 4; ++mi)
                #pragma unroll
                for (int ni = 0; ni < 4; ++ni)
                    acc[mi][ni] = MFMA16(af[mi], bfr[ni], acc[mi][ni]);
        }
    }

    float bcol[4];
    #pragma unroll
    for (int ni = 0; ni < 4; ++ni) bcol[ni] = bias[n0 + wx * 64 + ni * 16 + r];

    #pragma unroll
    for (int mi = 0; mi < 4; ++mi)
        #pragma unroll
        for (int ni = 0; ni < 4; ++ni)
            #pragma unroll
            for (int reg = 0; reg < 4; ++reg) {
                int row = m0 + wy * 64 + mi * 16 + q * 4 + reg;
                int col = n0 + wx * 64 + ni * 16 + r;
                float val = acc[mi][ni][reg] + bcol[ni];
                int bb = row >> 11, s = row & (S_LEN - 1);
                int hh = col >> 6, d = col & 63;
                if (z == 2) {
                    int kv = s & 63;
                    int kvp = ((kv & 15) << 2) | (kv >> 4);   // P-stash order
                    size_t off = (((size_t)bb * NH + hh) * 32 + (s >> 6)) * 4096
                               + (d >> 4) * 1024 + (kvp >> 5) * 512
                               + (((kvp & 31) >> 3) * 16 + (d & 15)) * 8 + (kvp & 7);
                    Vs[off] = f2bf(val);
                } else {
                    size_t off = (((size_t)bb * NH + hh) * 128 + (s >> 4)) * 1024
                               + (d >> 5) * 512
                               + (((d & 31) >> 3) * 16 + (s & 15)) * 8 + (d & 7);
                    if (z == 0) Qs[off] = f2bf(val * QSCALE);
                    else        Ks[off] = f2bf(val);
                }
            }
}

// ---------------- output projection GEMM: fp32 out, 128x64 tile, BK=64 --------
__global__ __launch_bounds__(256) void gemm_o(
    const unsigned short* __restrict__ X, const unsigned short* __restrict__ W,
    const float* __restrict__ bias, float* __restrict__ out)
{
    __shared__ unsigned short sA[128 * 64];   // 16 KB
    __shared__ unsigned short sB[64 * 64];    //  8 KB

    const int tid = threadIdx.x, lane = tid & 63, w = tid >> 6;
    const int wy = w & 1, wx = w >> 1, r = lane & 15, q = lane >> 4;
    const int m0 = blockIdx.x * 128, n0 = blockIdx.y * 64;
    const int lrow = tid >> 3, lkc = (tid & 7) * 8;

    const unsigned short* Xg = X + (size_t)(m0 + lrow) * D + lkc;
    const unsigned short* Wg = W + (size_t)(n0 + lrow) * D + lkc;

    f32x4 acc[4][2];
    #pragma unroll
    for (int mi = 0; mi < 4; ++mi)
        #pragma unroll
        for (int ni = 0; ni < 2; ++ni) acc[mi][ni] = (f32x4){0.f, 0.f, 0.f, 0.f};

    for (int k0 = 0; k0 < D; k0 += 64) {
        __syncthreads();
        gload16(Xg + k0,          sA + w * 512);
        gload16(Xg + 32 * D + k0, sA + 2048 + w * 512);
        gload16(Xg + 64 * D + k0, sA + 4096 + w * 512);
        gload16(Xg + 96 * D + k0, sA + 6144 + w * 512);
        gload16(Wg + k0,          sB + w * 512);
        gload16(Wg + 32 * D + k0, sB + 2048 + w * 512);
        __syncthreads();
        #pragma unroll
        for (int c = 0; c < 2; ++c) {
            short8 af[4], bfr[2];
            #pragma unroll
            for (int mi = 0; mi < 4; ++mi)
                af[mi] = *(const short8*)(sA + (wy * 64 + mi * 16 + r) * 64 + c * 32 + q * 8);
            #pragma unroll
            for (int ni = 0; ni < 2; ++ni)
                bfr[ni] = *(const short8*)(sB + (wx * 32 + ni * 16 + r) * 64 + c * 32 + q * 8);
            #pragma unroll
            for (int mi = 0; mi < 4; ++mi)
                #pragma unroll
                for (int ni = 0; ni < 2; ++ni)
                    acc[mi][ni] = MFMA16(af[mi], bfr[ni], acc[mi][ni]);
        }
    }

    float bcol[2];
    #pragma unroll
    for (int ni = 0; ni < 2; ++ni) bcol[ni] = bias[n0 + wx * 32 + ni * 16 + r];

    #pragma unroll
    for (int mi = 0; mi < 4; ++mi)
        #pragma unroll
        for (int ni = 0; ni < 2; ++ni)
            #pragma unroll
            for (int reg = 0; reg < 4; ++reg) {
                int row = m0 + wy * 64 + mi * 16 + q * 4 + reg;
                int col = n0 + wx * 32 + ni * 16 + r;
                out[(size_t)row * D + col] = acc[mi][ni][reg] + bcol[ni];
            }
}

// ---------------- attention: coalesced fragment loads from L2, barrier-free ---
__device__ __attribute__((always_inline)) inline void load_kfrag(
    const unsigned short* __restrict__ Kb, int blk16, int lane, short8 (&kf)[4][2])
{
    #pragma unroll
    for (int j = 0; j < 4; ++j)
        #pragma unroll
        for (int c = 0; c < 2; ++c)
            kf[j][c] = *(const short8*)(Kb + (size_t)(blk16 + j) * 1024 + c * 512 + lane * 8);
}

__device__ __attribute__((always_inline)) inline void attn_step(
    const unsigned short* __restrict__ Vb, int kvt, int lane, int r, int q,
    const short8 (&qf)[2][2], const short8 (&kf)[4][2],
    f32x4 (&O)[2][4], float (&psum)[2][4], unsigned short* __restrict__ sPw)
{
    // V^T frags for current tile (kv'-permuted layout matches the P stash)
    short8 vf[4][2];
    #pragma unroll
    for (int nb = 0; nb < 4; ++nb)
        #pragma unroll
        for (int p = 0; p < 2; ++p)
            vf[nb][p] = *(const short8*)(Vb + (size_t)kvt * 4096 + nb * 1024 + p * 512 + lane * 8);

    // scores (C-layout: qrow = q*4+reg, kv col = 16j+r)
    f32x4 sc[2][4];
    #pragma unroll
    for (int j = 0; j < 4; ++j)
        #pragma unroll
        for (int rb = 0; rb < 2; ++rb) {
            f32x4 t = (f32x4){0.f, 0.f, 0.f, 0.f};
            t = MFMA16(qf[rb][0], kf[j][0], t);
            t = MFMA16(qf[rb][1], kf[j][1], t);
            sc[rb][j] = t;
        }

    // p = 2^score; partial row-sums; packed P stash: col' = 4r + j -> one b64
    #pragma unroll
    for (int rb = 0; rb < 2; ++rb)
        #pragma unroll
        for (int reg = 0; reg < 4; ++reg) {
            float p0 = EXP2F(sc[rb][0][reg]);
            float p1 = EXP2F(sc[rb][1][reg]);
            float p2 = EXP2F(sc[rb][2][reg]);
            float p3 = EXP2F(sc[rb][3][reg]);
            psum[rb][reg] += (p0 + p1) + (p2 + p3);
            int row = rb * 16 + q * 4 + reg;
            ushort4 pk;
            pk.x = f2bf(p0); pk.y = f2bf(p1); pk.z = f2bf(p2); pk.w = f2bf(p3);
            *(ushort4*)(sPw + row * 72 + 4 * r) = pk;
        }

    // P as A-operand (same-wave LDS roundtrip; k' order matches V layout)
    short8 pf[2][2];
    #pragma unroll
    for (int rb = 0; rb < 2; ++rb) {
        pf[rb][0] = *(const short8*)(sPw + (rb * 16 + r) * 72 + q * 8);
        pf[rb][1] = *(const short8*)(sPw + (rb * 16 + r) * 72 + 32 + q * 8);
    }

    // O += P V
    #pragma unroll
    for (int nb = 0; nb < 4; ++nb)
        #pragma unroll
        for (int rb = 0; rb < 2; ++rb) {
            O[rb][nb] = MFMA16(pf[rb][0], vf[nb][0], O[rb][nb]);
            O[rb][nb] = MFMA16(pf[rb][1], vf[nb][1], O[rb][nb]);
        }
}

// Block = 128 Q rows x (head, batch); 4 waves, wave w owns rows 32w..32w+31.
// All Q/K/V fragment loads are coalesced b128 from the swizzled layouts.
// K frags double-buffered in registers (prefetch next tile during compute).
__global__ __launch_bounds__(256, 2) void attn_bf16(
    const unsigned short* __restrict__ Qs, const unsigned short* __restrict__ Ks,
    const unsigned short* __restrict__ Vs, unsigned short* __restrict__ AO)
{
    __shared__ unsigned short sP[4][32 * 72];   // per-wave 32x64 (+8 pad)

    const int tid = threadIdx.x, lane = tid & 63, w = tid >> 6;
    const int r = lane & 15, q = lane >> 4;
    const int q0 = blockIdx.x * 128;
    const int h = blockIdx.y, b = blockIdx.z;
    const int S = S_LEN;

    const unsigned short* Qb = Qs + ((size_t)b * NH + h) * 131072;
    const unsigned short* Kb = Ks + ((size_t)b * NH + h) * 131072;
    const unsigned short* Vb = Vs + ((size_t)b * NH + h) * 131072;
    unsigned short* sPw = sP[w];

    // Q fragments (coalesced, held in regs for the whole loop)
    short8 qf[2][2];
    #pragma unroll
    for (int rb = 0; rb < 2; ++rb)
        #pragma unroll
        for (int c = 0; c < 2; ++c)
            qf[rb][c] = *(const short8*)(Qb + (size_t)((q0 >> 4) + 2 * w + rb) * 1024
                                            + c * 512 + lane * 8);

    f32x4 O[2][4];
    float psum[2][4];
    #pragma unroll
    for (int rb = 0; rb < 2; ++rb)
        #pragma unroll
        for (int i = 0; i < 4; ++i) { O[rb][i] = (f32x4){0.f, 0.f, 0.f, 0.f}; psum[rb][i] = 0.f; }

    short8 kfA[4][2], kfB[4][2];
    load_kfrag(Kb, 0, lane, kfA);

    for (int kvt = 0; kvt < 32; kvt += 2) {
        int n1 = (kvt + 1 < 32) ? (kvt + 1) * 4 : 124;
        load_kfrag(Kb, n1, lane, kfB);
        attn_step(Vb, kvt, lane, r, q, qf, kfA, O, psum, sPw);
        int n2 = (kvt + 2 < 32) ? (kvt + 2) * 4 : 124;
        load_kfrag(Kb, n2, lane, kfA);
        attn_step(Vb, kvt + 1, lane, r, q, qf, kfB, O, psum, sPw);
    }

    // deferred l reduction (over the 16 kv-lane groups) + normalize + store
    float inv[2][4];
    #pragma unroll
    for (int rb = 0; rb < 2; ++rb)
        #pragma unroll
        for (int reg = 0; reg < 4; ++reg) {
            float l = psum[rb][reg];
            #pragma unroll
            for (int off = 8; off > 0; off >>= 1) l += __shfl_xor(l, off);
            inv[rb][reg] = 1.0f / l;
        }

    unsigned short* Ob = AO + ((size_t)b * S + q0 + 32 * w) * D + h * DK;
    #pragma unroll
    for (int rb = 0; rb < 2; ++rb)
        #pragma unroll
        for (int reg = 0; reg < 4; ++reg)
            #pragma unroll
            for (int nb = 0; nb < 4; ++nb)
                Ob[(size_t)(rb * 16 + q * 4 + reg) * D + nb * 16 + r] =
                    f2bf(O[rb][nb][reg] * inv[rb][reg]);
}

extern "C" void kernel_launch(void* const* d_in, const int* in_sizes, int n_in,
                              void* d_out, int out_size, void* d_ws, size_t ws_size,
                              hipStream_t stream)
{
    // inputs: v, k, q, Wv, bv, Wk, bk, Wq, bq, Wo, bo  (all fp32)
    const float* v  = (const float*)d_in[0];
    const float* k  = (const float*)d_in[1];
    const float* q  = (const float*)d_in[2];
    const float* Wv = (const float*)d_in[3];
    const float* bv = (const float*)d_in[4];
    const float* Wk = (const float*)d_in[5];
    const float* bk = (const float*)d_in[6];
    const float* Wq = (const float*)d_in[7];
    const float* bq = (const float*)d_in[8];
    const float* Wo = (const float*)d_in[9];
    const float* bo = (const float*)d_in[10];
    float* out = (float*)d_out;

    const int BS = in_sizes[0] / D;   // 4096
    const int S  = S_LEN;             // 2048
    const int B  = BS / S;            // 2

    char* ws = (char*)d_ws;
    unsigned short* qb  = (unsigned short*)(ws);                 // 8.4 MB
    unsigned short* kb  = (unsigned short*)(ws + 8388608);
    unsigned short* vb  = (unsigned short*)(ws + 16777216);
    unsigned short* Wqb = (unsigned short*)(ws + 25165824);      // 2 MB each
    unsigned short* Wkb = (unsigned short*)(ws + 27262976);
    unsigned short* Wvb = (unsigned short*)(ws + 29360128);
    unsigned short* Wob = (unsigned short*)(ws + 31457280);
    unsigned short* Qs  = (unsigned short*)(ws + 33554432);
    unsigned short* Ks  = (unsigned short*)(ws + 41943040);
    unsigned short* Vs  = (unsigned short*)(ws + 50331648);
    unsigned short* AO  = qb;   // qb dead after QKV projection

    dim3 blk(256);
    const int nInp = BS * D, nW = D * D;
    const int inpBlocks = nInp / 1024, wBlocks = nW / 1024;

    CvtP cp;
    cp.s[0] = q;  cp.d[0] = qb;
    cp.s[1] = k;  cp.d[1] = kb;
    cp.s[2] = v;  cp.d[2] = vb;
    cp.s[3] = Wq; cp.d[3] = Wqb;
    cp.s[4] = Wk; cp.d[4] = Wkb;
    cp.s[5] = Wv; cp.d[5] = Wvb;
    cp.s[6] = Wo; cp.d[6] = Wob;
    cvt_all<<<3 * inpBlocks + 4 * wBlocks, blk, 0, stream>>>(cp, inpBlocks, wBlocks);

    dim3 qkvgrid(BS / 128, D / 128, 3);  // 32 x 8 x 3 = 768 blocks (3/CU)
    gemm_qkv<<<qkvgrid, blk, 0, stream>>>(qb, kb, vb, Wqb, Wkb, Wvb,
                                          bq, bk, bv, Qs, Ks, Vs);

    dim3 agrid(S / 128, NH, B);          // 16 x 16 x 2 = 512 blocks (2/CU)
    attn_bf16<<<agrid, blk, 0, stream>>>(Qs, Ks, Vs, AO);

    dim3 ogrid(BS / 128, D / 64);        // 32 x 16 = 512 blocks (2/CU)
    gemm_o<<<ogrid, blk, 0, stream>>>(AO, Wob, bo, out);
}

// Round 9
// 237.288 us; speedup vs baseline: 1.1831x; 1.1831x over previous
//
#include <hip/hip_runtime.h>
#include <math.h>

#define D 1024
#define NH 16
#define DK 64
#define S_LEN 2048
// 0.125 (1/sqrt(Dk)) * log2(e): softmax computed in base-2 domain, no max-subtraction
#define QSCALE 0.18033688011112f

using short8 = __attribute__((ext_vector_type(8))) short;   // 8 x bf16 (4 VGPR)
using f32x4  = __attribute__((ext_vector_type(4))) float;   // MFMA accumulator

#define MFMA16(a, b, c) __builtin_amdgcn_mfma_f32_16x16x32_bf16((a), (b), (c), 0, 0, 0)
#define EXP2F(x) __builtin_amdgcn_exp2f(x)

__device__ inline unsigned short f2bf(float f) {
    union { float f; unsigned u; } v; v.f = f;
    unsigned r = v.u + 0x7fffu + ((v.u >> 16) & 1u);
    return (unsigned short)(r >> 16);
}

// async global->LDS, 16B/lane; LDS dest = ldsbase + lane*16 (wave-uniform base)
__device__ inline void gload16(const unsigned short* g, unsigned short* l) {
    __builtin_amdgcn_global_load_lds(
        (const __attribute__((address_space(1))) void*)g,
        (__attribute__((address_space(3))) void*)l, 16, 0, 0);
}

// ---------------- fused fp32 -> bf16 for q,k,v,Wq,Wk,Wv (6 tensors) -----------
struct CvtP {
    const float* s[6];
    unsigned short* d[6];
};
__global__ __launch_bounds__(256) void cvt_all(CvtP p, int inpBlocks, int wBlocks) {
    int bx = blockIdx.x;
    int seg, boff;
    if (bx < 3 * inpBlocks) { seg = bx / inpBlocks; boff = bx - seg * inpBlocks; }
    else { int t = bx - 3 * inpBlocks; seg = 3 + t / wBlocks; boff = t - (seg - 3) * wBlocks; }
    int i = (boff * 256 + threadIdx.x) * 4;
    float4 f = *(const float4*)(p.s[seg] + i);
    ushort4 u;
    u.x = f2bf(f.x); u.y = f2bf(f.y); u.z = f2bf(f.z); u.w = f2bf(f.w);
    *(ushort4*)(p.d[seg] + i) = u;
}

// ---------------- Wo fp32 -> bf16 B-fragment-swizzled -------------------------
// Wos off = (n>>4)*16384 + (k>>5)*512 + (((k&31)>>3)*16 + (n&15))*8 + (k&7)
// grid (64, 8) x 256 thr; lane r=n&15, j=(k&31)>>3; coalesced b128 writes.
__global__ __launch_bounds__(256) void wo_swz(const float* __restrict__ Wo,
                                              unsigned short* __restrict__ Wos) {
    const int t = threadIdx.x, lane = t & 63;
    const int r = lane & 15, j = (lane >> 4) & 3;
    const int nblk = blockIdx.x;                  // n>>4
    const int p = blockIdx.y * 4 + (t >> 6);      // k>>5
    const int n = nblk * 16 + r;
    const int k = p * 32 + j * 8;
    float4 f0 = *(const float4*)(Wo + (size_t)n * D + k);
    float4 f1 = *(const float4*)(Wo + (size_t)n * D + k + 4);
    short8 o;
    o[0] = f2bf(f0.x); o[1] = f2bf(f0.y); o[2] = f2bf(f0.z); o[3] = f2bf(f0.w);
    o[4] = f2bf(f1.x); o[5] = f2bf(f1.y); o[6] = f2bf(f1.z); o[7] = f2bf(f1.w);
    *(short8*)(Wos + (size_t)nblk * 16384 + p * 512 + lane * 8) = o;
}

// Fragment-swizzled layouts (per (b,h), element offsets in shorts):
//  Q_sw/K_sw: off = (s>>4)*1024 + (d>>5)*512 + (((d&31)>>3)*16 + (s&15))*8 + (d&7)
//  V_sw:      off = (s>>6)*4096 + (d>>4)*1024 + ((s&63)>>5)*512
//                   + (((s&31)>>3)*16 + (d&15))*8 + (s&7)
//  AO (A-swizzle, flat bs over B*S): off = (bs>>4)*16384 + (dm>>5)*512
//                   + (((dm&31)>>3)*16 + (bs&15))*8 + (dm&7)
// A wave's MFMA fragment load is one coalesced b128 at base + lane*16B.

// ---------------- fused QKV projection GEMM, 128x128 tile, BK=32 --------------
// R7-proven hot loop; NEW: LDS-bounce epilogue -> coalesced b128 swizzled stores.
__global__ __launch_bounds__(256) void gemm_qkv(
    const unsigned short* __restrict__ qb, const unsigned short* __restrict__ kb,
    const unsigned short* __restrict__ vb,
    const unsigned short* __restrict__ Wqb, const unsigned short* __restrict__ Wkb,
    const unsigned short* __restrict__ Wvb,
    const float* __restrict__ bq, const float* __restrict__ bk, const float* __restrict__ bv,
    unsigned short* __restrict__ Qs, unsigned short* __restrict__ Ks,
    unsigned short* __restrict__ Vs)
{
    __shared__ unsigned short smem[16384];   // 32 KB: sA=smem[0:4096), sB=[4096:8192); whole for bounce
    unsigned short* sA = smem;
    unsigned short* sB = smem + 4096;

    const int z = blockIdx.z;
    const unsigned short* X = (z == 0) ? qb : (z == 1) ? kb : vb;
    const unsigned short* W = (z == 0) ? Wqb : (z == 1) ? Wkb : Wvb;
    const float* bias = (z == 0) ? bq : (z == 1) ? bk : bv;

    const int tid = threadIdx.x, lane = tid & 63, w = tid >> 6;
    const int wy = w & 1, wx = w >> 1, r = lane & 15, q = lane >> 4;
    const int m0 = blockIdx.x * 128, n0 = blockIdx.y * 128;
    const int lrow = tid >> 2, lkc = (tid & 3) * 8;

    const unsigned short* Xg = X + (size_t)(m0 + lrow) * D + lkc;
    const unsigned short* Wg = W + (size_t)(n0 + lrow) * D + lkc;

    f32x4 acc[4][4];
    #pragma unroll
    for (int mi = 0; mi < 4; ++mi)
        #pragma unroll
        for (int ni = 0; ni < 4; ++ni) acc[mi][ni] = (f32x4){0.f, 0.f, 0.f, 0.f};

    for (int k0 = 0; k0 < D; k0 += 32) {
        __syncthreads();
        gload16(Xg + k0,          sA + w * 512);
        gload16(Xg + 64 * D + k0, sA + 2048 + w * 512);
        gload16(Wg + k0,          sB + w * 512);
        gload16(Wg + 64 * D + k0, sB + 2048 + w * 512);
        __syncthreads();
        short8 af[4], bfr[4];
        #pragma unroll
        for (int mi = 0; mi < 4; ++mi)
            af[mi] = *(const short8*)(sA + (wy * 64 + mi * 16 + r) * 32 + q * 8);
        #pragma unroll
        for (int ni = 0; ni < 4; ++ni)
            bfr[ni] = *(const short8*)(sB + (wx * 64 + ni * 16 + r) * 32 + q * 8);
        #pragma unroll
        for (int mi = 0; mi < 4; ++mi)
            #pragma unroll
            for (int ni = 0; ni < 4; ++ni)
                acc[mi][ni] = MFMA16(af[mi], bfr[ni], acc[mi][ni]);
    }

    float bcol[4];
    #pragma unroll
    for (int ni = 0; ni < 4; ++ni) bcol[ni] = bias[n0 + wx * 64 + ni * 16 + r];

    const int bb = m0 >> 11;             // batch (block never straddles)
    const int sBase = m0 & (S_LEN - 1);  // s of local row 0
    const int hh0 = n0 >> 6;             // first head in this block

    __syncthreads();   // last iter's LDS frag reads done; smem free for bounce

    if (z != 2) {
        const float sc = (z == 0) ? QSCALE : 1.0f;
        // scatter bf16 into LDS image of the block's 16 x 1024-short chunks
        #pragma unroll
        for (int mi = 0; mi < 4; ++mi)
            #pragma unroll
            for (int ni = 0; ni < 4; ++ni)
                #pragma unroll
                for (int reg = 0; reg < 4; ++reg) {
                    float val = (acc[mi][ni][reg] + bcol[ni]) * sc;
                    int off = (wx * 8 + wy * 4 + mi) * 1024 + (ni >> 1) * 512
                            + (((ni & 1) * 2 + (r >> 3)) * 16 + q * 4 + reg) * 8 + (r & 7);
                    smem[off] = f2bf(val);
                }
        __syncthreads();
        unsigned short* dst = (z == 0) ? Qs : Ks;
        #pragma unroll
        for (int kk = 0; kk < 8; ++kk) {
            int idx = tid + 256 * kk;              // b128 index, 0..2047
            int ci = idx >> 7, within = idx & 127;
            int hh_l = ci >> 3, sblk_l = ci & 7;
            size_t g = ((size_t)bb * NH + hh0 + hh_l) * 131072
                     + (size_t)((sBase >> 4) + sblk_l) * 1024 + within * 8;
            *(short8*)(dst + g) = *(const short8*)(smem + idx * 8);
        }
    } else {
        #pragma unroll
        for (int mi = 0; mi < 4; ++mi)
            #pragma unroll
            for (int ni = 0; ni < 4; ++ni)
                #pragma unroll
                for (int reg = 0; reg < 4; ++reg) {
                    float val = acc[mi][ni][reg] + bcol[ni];
                    int off = (wx * 2 + wy) * 4096 + ni * 1024 + (mi >> 1) * 512
                            + (((mi & 1) * 2 + (q >> 1)) * 16 + r) * 8 + (q & 1) * 4 + reg;
                    smem[off] = f2bf(val);
                }
        __syncthreads();
        #pragma unroll
        for (int kk = 0; kk < 8; ++kk) {
            int idx = tid + 256 * kk;
            int ci = idx >> 9, within = idx & 511;
            int hh_l = ci >> 1, vt_l = ci & 1;
            size_t g = ((size_t)bb * NH + hh0 + hh_l) * 131072
                     + (size_t)((sBase >> 6) + vt_l) * 4096 + within * 8;
            *(short8*)(Vs + g) = *(const short8*)(smem + idx * 8);
        }
    }
}

// ---------------- output projection: zero-LDS, zero-barrier -------------------
// A-frags from swizzled AO, B-frags from swizzled Wos; register double-buffer.
// 128x64 tile, 4 waves 2x2 (each 64x32); fp32 row-major out (4-line coalesced).
__global__ __launch_bounds__(256, 2) void gemm_o(
    const unsigned short* __restrict__ AO, const unsigned short* __restrict__ Wos,
    const float* __restrict__ bias, float* __restrict__ out)
{
    const int tid = threadIdx.x, lane = tid & 63, w = tid >> 6;
    const int wy = w & 1, wx = w >> 1, r = lane & 15, q = lane >> 4;
    const int m0 = blockIdx.x * 128, n0 = blockIdx.y * 64;

    const unsigned short* Ab = AO + (size_t)((m0 >> 4) + wy * 4) * 16384 + lane * 8;
    const unsigned short* Bb = Wos + (size_t)((n0 >> 4) + wx * 2) * 16384 + lane * 8;

    f32x4 acc[4][2];
    #pragma unroll
    for (int mi = 0; mi < 4; ++mi)
        #pragma unroll
        for (int ni = 0; ni < 2; ++ni) acc[mi][ni] = (f32x4){0.f, 0.f, 0.f, 0.f};

    short8 afA[4], bfA[2], afB[4], bfB[2];
    #pragma unroll
    for (int mi = 0; mi < 4; ++mi) afA[mi] = *(const short8*)(Ab + (size_t)mi * 16384);
    #pragma unroll
    for (int ni = 0; ni < 2; ++ni) bfA[ni] = *(const short8*)(Bb + (size_t)ni * 16384);

    for (int p = 0; p < 32; p += 2) {
        int p1 = (p + 1 < 32) ? p + 1 : 31;
        #pragma unroll
        for (int mi = 0; mi < 4; ++mi) afB[mi] = *(const short8*)(Ab + (size_t)mi * 16384 + p1 * 512);
        #pragma unroll
        for (int ni = 0; ni < 2; ++ni) bfB[ni] = *(const short8*)(Bb + (size_t)ni * 16384 + p1 * 512);
        #pragma unroll
        for (int mi = 0; mi < 4; ++mi)
            #pragma unroll
            for (int ni = 0; ni < 2; ++ni)
                acc[mi][ni] = MFMA16(afA[mi], bfA[ni], acc[mi][ni]);
        int p2 = (p + 2 < 32) ? p + 2 : 31;
        #pragma unroll
        for (int mi = 0; mi < 4; ++mi) afA[mi] = *(const short8*)(Ab + (size_t)mi * 16384 + p2 * 512);
        #pragma unroll
        for (int ni = 0; ni < 2; ++ni) bfA[ni] = *(const short8*)(Bb + (size_t)ni * 16384 + p2 * 512);
        #pragma unroll
        for (int mi = 0; mi < 4; ++mi)
            #pragma unroll
            for (int ni = 0; ni < 2; ++ni)
                acc[mi][ni] = MFMA16(afB[mi], bfB[ni], acc[mi][ni]);
    }

    float bcol[2];
    #pragma unroll
    for (int ni = 0; ni < 2; ++ni) bcol[ni] = bias[n0 + wx * 32 + ni * 16 + r];

    #pragma unroll
    for (int mi = 0; mi < 4; ++mi)
        #pragma unroll
        for (int ni = 0; ni < 2; ++ni)
            #pragma unroll
            for (int reg = 0; reg < 4; ++reg) {
                int row = m0 + wy * 64 + mi * 16 + q * 4 + reg;
                int col = n0 + wx * 32 + ni * 16 + r;
                out[(size_t)row * D + col] = acc[mi][ni][reg] + bcol[ni];
            }
}

// ---------------- attention: R7-proven hot loop; swizzled-AO bounce epilogue --
__device__ __attribute__((always_inline)) inline void load_kfrag(
    const unsigned short* __restrict__ Kb, int blk16, int lane, short8 (&kf)[4][2])
{
    #pragma unroll
    for (int j = 0; j < 4; ++j)
        #pragma unroll
        for (int c = 0; c < 2; ++c)
            kf[j][c] = *(const short8*)(Kb + (size_t)(blk16 + j) * 1024 + c * 512 + lane * 8);
}

__device__ __attribute__((always_inline)) inline void attn_step(
    const unsigned short* __restrict__ Vb, int kvt, int lane, int r, int q,
    const short8 (&qf)[2][2], const short8 (&kf)[4][2],
    f32x4 (&O)[2][4], float (&psum)[2][4], unsigned short* __restrict__ sPw)
{
    // V^T frags for current tile (issued early; consumed after softmax)
    short8 vf[4][2];
    #pragma unroll
    for (int nb = 0; nb < 4; ++nb)
        #pragma unroll
        for (int p = 0; p < 2; ++p)
            vf[nb][p] = *(const short8*)(Vb + (size_t)kvt * 4096 + nb * 1024 + p * 512 + lane * 8);

    // scores (C-layout: qrow = q*4+reg, kv col = 16j+r)
    f32x4 sc[2][4];
    #pragma unroll
    for (int j = 0; j < 4; ++j)
        #pragma unroll
        for (int rb = 0; rb < 2; ++rb) {
            f32x4 t = (f32x4){0.f, 0.f, 0.f, 0.f};
            t = MFMA16(qf[rb][0], kf[j][0], t);
            t = MFMA16(qf[rb][1], kf[j][1], t);
            sc[rb][j] = t;
        }

    // p = 2^score; partial row-sums; stash bf16 P (per-wave LDS, no barrier)
    #pragma unroll
    for (int rb = 0; rb < 2; ++rb)
        #pragma unroll
        for (int reg = 0; reg < 4; ++reg) {
            float p0 = EXP2F(sc[rb][0][reg]);
            float p1 = EXP2F(sc[rb][1][reg]);
            float p2 = EXP2F(sc[rb][2][reg]);
            float p3 = EXP2F(sc[rb][3][reg]);
            psum[rb][reg] += (p0 + p1) + (p2 + p3);
            int row = rb * 16 + q * 4 + reg;
            sPw[row * 72 + r]      = f2bf(p0);
            sPw[row * 72 + 16 + r] = f2bf(p1);
            sPw[row * 72 + 32 + r] = f2bf(p2);
            sPw[row * 72 + 48 + r] = f2bf(p3);
        }

    // P as A-operand (same-wave LDS roundtrip)
    short8 pf[2][2];
    #pragma unroll
    for (int rb = 0; rb < 2; ++rb) {
        pf[rb][0] = *(const short8*)(sPw + (rb * 16 + r) * 72 + q * 8);
        pf[rb][1] = *(const short8*)(sPw + (rb * 16 + r) * 72 + 32 + q * 8);
    }

    // O += P V
    #pragma unroll
    for (int nb = 0; nb < 4; ++nb)
        #pragma unroll
        for (int rb = 0; rb < 2; ++rb) {
            O[rb][nb] = MFMA16(pf[rb][0], vf[nb][0], O[rb][nb]);
            O[rb][nb] = MFMA16(pf[rb][1], vf[nb][1], O[rb][nb]);
        }
}

// Block = 128 Q rows x (head, batch); 4 waves, wave w owns rows 32w..32w+31.
__global__ __launch_bounds__(256, 2) void attn_bf16(
    const unsigned short* __restrict__ Qs, const unsigned short* __restrict__ Ks,
    const unsigned short* __restrict__ Vs, unsigned short* __restrict__ AO)
{
    __shared__ unsigned short sP[4][32 * 72];   // per-wave 32x64 (+8 pad)

    const int tid = threadIdx.x, lane = tid & 63, w = tid >> 6;
    const int r = lane & 15, q = lane >> 4;
    const int q0 = blockIdx.x * 128;
    const int h = blockIdx.y, b = blockIdx.z;

    const unsigned short* Qb = Qs + ((size_t)b * NH + h) * 131072;
    const unsigned short* Kb = Ks + ((size_t)b * NH + h) * 131072;
    const unsigned short* Vb = Vs + ((size_t)b * NH + h) * 131072;
    unsigned short* sPw = sP[w];

    // Q fragments (coalesced, held in regs for the whole loop)
    short8 qf[2][2];
    #pragma unroll
    for (int rb = 0; rb < 2; ++rb)
        #pragma unroll
        for (int c = 0; c < 2; ++c)
            qf[rb][c] = *(const short8*)(Qb + (size_t)((q0 >> 4) + 2 * w + rb) * 1024
                                            + c * 512 + lane * 8);

    f32x4 O[2][4];
    float psum[2][4];
    #pragma unroll
    for (int rb = 0; rb < 2; ++rb)
        #pragma unroll
        for (int i = 0; i < 4; ++i) { O[rb][i] = (f32x4){0.f, 0.f, 0.f, 0.f}; psum[rb][i] = 0.f; }

    short8 kfA[4][2], kfB[4][2];
    load_kfrag(Kb, 0, lane, kfA);

    for (int kvt = 0; kvt < 32; kvt += 2) {
        int n1 = (kvt + 1 < 32) ? (kvt + 1) * 4 : 124;
        load_kfrag(Kb, n1, lane, kfB);
        attn_step(Vb, kvt, lane, r, q, qf, kfA, O, psum, sPw);
        int n2 = (kvt + 2 < 32) ? (kvt + 2) * 4 : 124;
        load_kfrag(Kb, n2, lane, kfA);
        attn_step(Vb, kvt + 1, lane, r, q, qf, kfB, O, psum, sPw);
    }

    // deferred l reduction + normalize
    float inv[2][4];
    #pragma unroll
    for (int rb = 0; rb < 2; ++rb)
        #pragma unroll
        for (int reg = 0; reg < 4; ++reg) {
            float l = psum[rb][reg];
            #pragma unroll
            for (int off = 8; off > 0; off >>= 1) l += __shfl_xor(l, off);
            inv[rb][reg] = 1.0f / l;
        }

    // epilogue: per-wave LDS bounce -> coalesced b128 stores, A-swizzled AO
    #pragma unroll
    for (int rb = 0; rb < 2; ++rb)
        #pragma unroll
        for (int reg = 0; reg < 4; ++reg)
            #pragma unroll
            for (int nb = 0; nb < 4; ++nb) {
                int ld = nb * 16 + r;
                int off = (rb * 2 + (nb >> 1)) * 512
                        + (((nb & 1) * 2 + (r >> 3)) * 16 + q * 4 + reg) * 8 + (r & 7);
                sPw[off] = f2bf(O[rb][nb][reg] * inv[rb][reg]);
                (void)ld;
            }
    #pragma unroll
    for (int kk = 0; kk < 4; ++kk) {
        int rb = kk >> 1, panel = kk & 1;
        size_t g = (size_t)(b * 128 + (q0 >> 4) + 2 * w + rb) * 16384
                 + (size_t)(h * 2 + panel) * 512 + lane * 8;
        *(short8*)(AO + g) = *(const short8*)(sPw + kk * 512 + lane * 8);
    }
}

extern "C" void kernel_launch(void* const* d_in, const int* in_sizes, int n_in,
                              void* d_out, int out_size, void* d_ws, size_t ws_size,
                              hipStream_t stream)
{
    // inputs: v, k, q, Wv, bv, Wk, bk, Wq, bq, Wo, bo  (all fp32)
    const float* v  = (const float*)d_in[0];
    const float* k  = (const float*)d_in[1];
    const float* q  = (const float*)d_in[2];
    const float* Wv = (const float*)d_in[3];
    const float* bv = (const float*)d_in[4];
    const float* Wk = (const float*)d_in[5];
    const float* bk = (const float*)d_in[6];
    const float* Wq = (const float*)d_in[7];
    const float* bq = (const float*)d_in[8];
    const float* Wo = (const float*)d_in[9];
    const float* bo = (const float*)d_in[10];
    float* out = (float*)d_out;

    const int BS = in_sizes[0] / D;   // 4096
    (void)BS;

    char* ws = (char*)d_ws;
    unsigned short* qb  = (unsigned short*)(ws);                 // 8.4 MB
    unsigned short* kb  = (unsigned short*)(ws + 8388608);
    unsigned short* vb  = (unsigned short*)(ws + 16777216);
    unsigned short* Wqb = (unsigned short*)(ws + 25165824);      // 2 MB each
    unsigned short* Wkb = (unsigned short*)(ws + 27262976);
    unsigned short* Wvb = (unsigned short*)(ws + 29360128);
    unsigned short* Wos = (unsigned short*)(ws + 31457280);      // swizzled Wo
    unsigned short* Qs  = (unsigned short*)(ws + 33554432);
    unsigned short* Ks  = (unsigned short*)(ws + 41943040);
    unsigned short* Vs  = (unsigned short*)(ws + 50331648);
    unsigned short* AO  = qb;   // qb dead after QKV projection; AO is A-swizzled

    dim3 blk(256);
    const int nInp = 4096 * D, nW = D * D;
    const int inpBlocks = nInp / 1024, wBlocks = nW / 1024;

    CvtP cp;
    cp.s[0] = q;  cp.d[0] = qb;
    cp.s[1] = k;  cp.d[1] = kb;
    cp.s[2] = v;  cp.d[2] = vb;
    cp.s[3] = Wq; cp.d[3] = Wqb;
    cp.s[4] = Wk; cp.d[4] = Wkb;
    cp.s[5] = Wv; cp.d[5] = Wvb;
    cvt_all<<<3 * inpBlocks + 3 * wBlocks, blk, 0, stream>>>(cp, inpBlocks, wBlocks);

    dim3 wgrid(64, 8);
    wo_swz<<<wgrid, blk, 0, stream>>>(Wo, Wos);

    dim3 qkvgrid(4096 / 128, D / 128, 3);  // 32 x 8 x 3 = 768 blocks (3/CU)
    gemm_qkv<<<qkvgrid, blk, 0, stream>>>(qb, kb, vb, Wqb, Wkb, Wvb,
                                          bq, bk, bv, Qs, Ks, Vs);

    dim3 agrid(S_LEN / 128, NH, 2);        // 16 x 16 x 2 = 512 blocks (2/CU)
    attn_bf16<<<agrid, blk, 0, stream>>>(Qs, Ks, Vs, AO);

    dim3 ogrid(4096 / 128, D / 64);        // 32 x 16 = 512 blocks (2/CU)
    gemm_o<<<ogrid, blk, 0, stream>>>(AO, Wos, bo, out);
}